// Round 1
// baseline (37396.246 us; speedup 1.0000x reference)
//
#include <hip/hip_runtime.h>

// Problem constants (fixed by reference)
#define T_STEPS 16384
#define HID     512
#define NWG     32      // workgroups; each owns HID/NWG = 16 hidden units
#define JPW     16      // units per WG
#define RING_D  8       // ring depth (steps); WG skew provably < 2
#define RING_W  1024    // words per slot: 512 elements x 2 tagged words

// --- tagged-word ring helpers: each 32-bit word = 16 data bits | 16-bit tag.
// tag(h_t) = t+2 (tag 1 = initial h0, tag 0 = empty). Self-validating words
// mean publish->consume needs NO fence and NO separate flag round trip.
__device__ __forceinline__ unsigned ld_ring(const unsigned* p) {
  return __hip_atomic_load(p, __ATOMIC_RELAXED, __HIP_MEMORY_SCOPE_AGENT);
}
__device__ __forceinline__ void st_ring(unsigned* p, unsigned v) {
  __hip_atomic_store(p, v, __ATOMIC_RELAXED, __HIP_MEMORY_SCOPE_AGENT);
}
__device__ __forceinline__ float sigf(float x) {
  return __fdividef(1.f, 1.f + __expf(-x));
}
__device__ __forceinline__ float tanhfast(float x) {
  x = fminf(fmaxf(x, -15.f), 15.f);
  float e = __expf(2.f * x);
  return 1.f - __fdividef(2.f, e + 1.f);
}

// Init: out[t] = bl (scan kernel atomicAdds partial dots on top), ring zeroed
// except slot RING_D-1 which holds h_{-1} = h0 with tag 1. Single kernel, no
// intra-kernel ordering hazard (each word written exactly once).
__global__ void init_kernel(float* __restrict__ out, unsigned* __restrict__ ring,
                            const float* __restrict__ h0, const float* __restrict__ bl) {
  int i = blockIdx.x * blockDim.x + threadIdx.x;
  if (i < T_STEPS) out[i] = bl[0];
  if (i < RING_D * RING_W) {
    unsigned v = 0;
    int slot = i >> 10;
    int w = i & (RING_W - 1);
    if (slot == RING_D - 1) {
      unsigned bits = __float_as_uint(h0[w >> 1]);
      v = (w & 1) ? ((bits << 16) | 1u) : ((bits & 0xFFFF0000u) | 1u);
    }
    ring[i] = v;
  }
}

// Persistent scan. Thread layout: tid = jl*16 + s; jl = local unit (0..15),
// s = k-split (0..15) covering h[k] for k in [s*32, s*32+32).
// Recurrent weights live in VGPRs (3 gates x 32 = 96 regs/thread).
__global__ __launch_bounds__(256, 1) void lstm_scan(
    const float* __restrict__ x,  const float* __restrict__ c0,
    const float* __restrict__ Wi, const float* __restrict__ bi,
    const float* __restrict__ Wf1,const float* __restrict__ bf1,
    const float* __restrict__ Wf2,const float* __restrict__ bf2,
    const float* __restrict__ Wg1,const float* __restrict__ bg1,
    const float* __restrict__ Wg2,const float* __restrict__ bg2,
    const float* __restrict__ Wo1,const float* __restrict__ bo1,
    const float* __restrict__ Wo2,const float* __restrict__ bo2,
    const float* __restrict__ Wl, float* __restrict__ out,
    unsigned* __restrict__ ring)
{
  const int tid = threadIdx.x;
  const int jl  = tid >> 4;
  const int s   = tid & 15;
  const int jg  = blockIdx.x * JPW + jl;

  // h staging: chunk s lives at dword s*36 (32 data + 4 pad) -> ds_read_b128
  // bank pattern is 2-way (free, m136) instead of 16-way without padding.
  __shared__ __align__(16) float hbuf[2][16 * 36];
  __shared__ float4 xbuf[2][12];   // one 48-float x row, double-buffered

  // ---- load recurrent weight slices into registers (one-time) ----
  float4 wf[8], wg[8], wo[8];
  {
    const float4* pf = (const float4*)(Wf2 + jg * HID + s * 32);
    const float4* pg = (const float4*)(Wg2 + jg * HID + s * 32);
    const float4* po = (const float4*)(Wo2 + jg * HID + s * 32);
#pragma unroll
    for (int r = 0; r < 8; ++r) { wf[r] = pf[r]; wg[r] = pg[r]; wo[r] = po[r]; }
  }
  // ---- x-projection weights: s==0 -> i-gate (32 wide), s==1/2/3 -> f/g/o (16 wide)
  float4 wx[8];
  float xb = 0.f;
#pragma unroll
  for (int r = 0; r < 8; ++r) wx[r] = make_float4(0.f, 0.f, 0.f, 0.f);
  if (s == 0) {
    const float4* p = (const float4*)(Wi + jg * 32);
#pragma unroll
    for (int r = 0; r < 8; ++r) wx[r] = p[r];
    xb = bi[jg];
  } else if (s == 1) {
    const float4* p = (const float4*)(Wf1 + jg * 16);
#pragma unroll
    for (int r = 0; r < 4; ++r) wx[r] = p[r];
    xb = bf1[jg] + bf2[jg];
  } else if (s == 2) {
    const float4* p = (const float4*)(Wg1 + jg * 16);
#pragma unroll
    for (int r = 0; r < 4; ++r) wx[r] = p[r];
    xb = bg1[jg] + bg2[jg];
  } else if (s == 3) {
    const float4* p = (const float4*)(Wo1 + jg * 16);
#pragma unroll
    for (int r = 0; r < 4; ++r) wx[r] = p[r];
    xb = bo1[jg] + bo2[jg];
  }

  float cst = c0[jg];          // cell state (meaningful on s==0 lanes)
  const float wl = Wl[jg];

  // x prefetch, distance 2: xbuf[0] <- x[0]; xpre <- x[1]
  float4 xpre = make_float4(0.f, 0.f, 0.f, 0.f);
  if (tid < 12) {
    xbuf[0][tid] = *(const float4*)(x + 4 * tid);
    xpre = *(const float4*)(x + 48 + 4 * tid);
  }
  __syncthreads();

  for (int t = 0; t < T_STEPS; ++t) {
    // 1) stage x[t+1] (regs->LDS), kick off load of x[t+2]
    if (tid < 12) {
      xbuf[(t + 1) & 1][tid] = xpre;
      int tn = (t + 2 < T_STEPS) ? t + 2 : T_STEPS - 1;
      xpre = *(const float4*)(x + tn * 48 + 4 * tid);
    }
    // 2) x projections — computed in the shadow of h_{t-1} visibility latency
    float pr = xb;
    if (s < 4) {
      const float4* xv = &xbuf[t & 1][(s == 0) ? 4 : 0];
#pragma unroll
      for (int r = 0; r < 4; ++r) {
        float4 v = xv[r], w = wx[r];
        pr = fmaf(w.x, v.x, pr); pr = fmaf(w.y, v.y, pr);
        pr = fmaf(w.z, v.z, pr); pr = fmaf(w.w, v.w, pr);
      }
      if (s == 0) {
#pragma unroll
        for (int r = 4; r < 8; ++r) {
          float4 v = xv[r], w = wx[r];
          pr = fmaf(w.x, v.x, pr); pr = fmaf(w.y, v.y, pr);
          pr = fmaf(w.z, v.z, pr); pr = fmaf(w.w, v.w, pr);
        }
      }
    }
    float accf = (s == 1) ? pr : 0.f;
    float accg = (s == 2) ? pr : 0.f;
    float acco = (s == 3) ? pr : 0.f;
    const float ipre = pr;   // i-gate preact (valid on s==0)

    // 3) poll h_{t-1}: thread tid owns ring words [4tid,4tid+4) = elems 2tid,2tid+1
    const unsigned want = (unsigned)(t + 1);          // tag of h_{t-1}
    const unsigned* pw =
        ring + (((unsigned)(t - 1)) & (RING_D - 1)) * RING_W + 4 * tid;
    unsigned a, b, c2, d2;
    do {
      a  = ld_ring(pw);     b  = ld_ring(pw + 1);
      c2 = ld_ring(pw + 2); d2 = ld_ring(pw + 3);
    } while (((a ^ want) | (b ^ want) | (c2 ^ want) | (d2 ^ want)) & 0xFFFFu);
    unsigned bits0 = (a  & 0xFFFF0000u) | (b  >> 16);
    unsigned bits1 = (c2 & 0xFFFF0000u) | (d2 >> 16);
    {
      int idx = 2 * tid + 4 * (tid >> 4);             // swizzled: elem e -> e + 4*(e>>5)
      *(float2*)(&hbuf[t & 1][idx]) =
          make_float2(__uint_as_float(bits0), __uint_as_float(bits1));
    }
    __syncthreads();   // the ONLY barrier per step

    // 4) gate dots: 3 gates x 32 k-elems from VGPR weights, h from LDS
    const float* hb = &hbuf[t & 1][s * 36];
#pragma unroll
    for (int r = 0; r < 8; ++r) {
      float4 hv = *(const float4*)(hb + 4 * r);
      accf = fmaf(wf[r].x, hv.x, accf); accf = fmaf(wf[r].y, hv.y, accf);
      accf = fmaf(wf[r].z, hv.z, accf); accf = fmaf(wf[r].w, hv.w, accf);
      accg = fmaf(wg[r].x, hv.x, accg); accg = fmaf(wg[r].y, hv.y, accg);
      accg = fmaf(wg[r].z, hv.z, accg); accg = fmaf(wg[r].w, hv.w, accg);
      acco = fmaf(wo[r].x, hv.x, acco); acco = fmaf(wo[r].y, hv.y, acco);
      acco = fmaf(wo[r].z, hv.z, acco); acco = fmaf(wo[r].w, hv.w, acco);
    }
    // 5) butterfly reduce over the 16 k-split lanes (all lanes get the sum)
#pragma unroll
    for (int m = 1; m <= 8; m <<= 1) {
      accf += __shfl_xor(accf, m, 16);
      accg += __shfl_xor(accg, m, 16);
      acco += __shfl_xor(acco, m, 16);
    }
    // 6) gates + state update (computed on all lanes; only s==0 is meaningful)
    float f  = sigf(accf);
    float g  = tanhfast(accg);
    float o  = sigf(acco);
    float it = sigf(ipre);
    cst = fmaf(f, cst, it * g);
    float hj = o * tanhfast(cst);

    // 7) publish h_t as two tagged words (relaxed agent-scope; self-validating)
    if (s == 0) {
      unsigned bits = __float_as_uint(hj);
      unsigned tag  = (unsigned)(t + 2);
      unsigned* dst = ring + (t & (RING_D - 1)) * RING_W + 2 * jg;
      st_ring(dst,     (bits & 0xFFFF0000u) | tag);
      st_ring(dst + 1, (bits << 16) | tag);
    }
    // 8) out[t] partial: wave-reduce the 4 owner lanes, one atomicAdd per wave
    float val = (s == 0) ? wl * hj : 0.f;
    val += __shfl_xor(val, 16, 64);
    val += __shfl_xor(val, 32, 64);
    if ((tid & 63) == 0) atomicAdd(out + t, val);
  }
}

extern "C" void kernel_launch(void* const* d_in, const int* in_sizes, int n_in,
                              void* d_out, int out_size, void* d_ws, size_t ws_size,
                              hipStream_t stream) {
  const float* x   = (const float*)d_in[0];
  const float* h0  = (const float*)d_in[1];
  const float* c0  = (const float*)d_in[2];
  const float* Wi  = (const float*)d_in[3];
  const float* bi  = (const float*)d_in[4];
  const float* Wf1 = (const float*)d_in[5];
  const float* bf1 = (const float*)d_in[6];
  const float* Wf2 = (const float*)d_in[7];
  const float* bf2 = (const float*)d_in[8];
  const float* Wg1 = (const float*)d_in[9];
  const float* bg1 = (const float*)d_in[10];
  const float* Wg2 = (const float*)d_in[11];
  const float* bg2 = (const float*)d_in[12];
  const float* Wo1 = (const float*)d_in[13];
  const float* bo1 = (const float*)d_in[14];
  const float* Wo2 = (const float*)d_in[15];
  const float* bo2 = (const float*)d_in[16];
  const float* Wl  = (const float*)d_in[17];
  const float* bl  = (const float*)d_in[18];
  float* out = (float*)d_out;
  unsigned* ring = (unsigned*)d_ws;   // 8 slots x 4 KiB = 32 KiB used

  hipLaunchKernelGGL(init_kernel, dim3(64), dim3(256), 0, stream, out, ring, h0, bl);
  hipLaunchKernelGGL(lstm_scan, dim3(NWG), dim3(256), 0, stream,
                     x, c0, Wi, bi, Wf1, bf1, Wf2, bf2, Wg1, bg1, Wg2, bg2,
                     Wo1, bo1, Wo2, bo2, Wl, out, ring);
}

// Round 2
// 27718.680 us; speedup vs baseline: 1.3491x; 1.3491x over previous
//
#include <hip/hip_runtime.h>

// Problem constants (fixed by reference)
#define T_STEPS 16384
#define HID     512
#define NWG     32      // workgroups; each owns HID/NWG = 16 hidden units
#define JPW     16      // units per WG
#define RING_D  8       // ring depth (steps); WG skew provably < 2
#define RING_W  1024    // words per slot: 512 elements x 2 tagged words
#define NPART   (NWG * 4)   // one partial per wave per step

// --- tagged-word ring helpers: each 32-bit word = 16 data bits | 16-bit tag.
// tag(h_t) = t+2 (tag 1 = initial h0, tag 0 = empty). Self-validating words
// mean publish->consume needs NO fence and NO separate flag round trip.
// (0xAAAA poison tag = 43690 > max tag 16385, can never false-match.)
__device__ __forceinline__ unsigned ld_ring(const unsigned* p) {
  return __hip_atomic_load(p, __ATOMIC_RELAXED, __HIP_MEMORY_SCOPE_AGENT);
}
__device__ __forceinline__ void st_ring(unsigned* p, unsigned v) {
  __hip_atomic_store(p, v, __ATOMIC_RELAXED, __HIP_MEMORY_SCOPE_AGENT);
}
__device__ __forceinline__ float sigf(float x) {
  return __fdividef(1.f, 1.f + __expf(-x));
}
__device__ __forceinline__ float tanhfast(float x) {
  x = fminf(fmaxf(x, -15.f), 15.f);
  float e = __expf(2.f * x);
  return 1.f - __fdividef(2.f, e + 1.f);
}

// Init: out[t] = bl (finalize overwrites in partials mode; atomic fallback
// accumulates on top), ring zeroed except slot RING_D-1 = h0 with tag 1.
__global__ void init_kernel(float* __restrict__ out, unsigned* __restrict__ ring,
                            const float* __restrict__ h0, const float* __restrict__ bl) {
  int i = blockIdx.x * blockDim.x + threadIdx.x;
  if (i < T_STEPS) out[i] = bl[0];
  if (i < RING_D * RING_W) {
    unsigned v = 0;
    int slot = i >> 10;
    int w = i & (RING_W - 1);
    if (slot == RING_D - 1) {
      unsigned bits = __float_as_uint(h0[w >> 1]);
      v = (w & 1) ? ((bits << 16) | 1u) : ((bits & 0xFFFF0000u) | 1u);
    }
    ring[i] = v;
  }
}

// out[t] = bl + sum of 128 per-wave partials. Coalesced column reads.
__global__ void finalize_kernel(const float* __restrict__ part,
                                const float* __restrict__ bl,
                                float* __restrict__ out) {
  int t = blockIdx.x * blockDim.x + threadIdx.x;
  float s = bl[0];
#pragma unroll 8
  for (int i = 0; i < NPART; ++i) s += part[i * T_STEPS + t];
  out[t] = s;
}

// Persistent scan. Thread layout: tid = jl*16 + s; jl = local unit (0..15),
// s = k-split (0..15) covering h[k] for k in [s*32, s*32+32).
// Recurrent weights live in VGPRs (3 gates x 32 = 96 regs/thread).
// NO atomics in the loop: the per-step __syncthreads drains vmcnt(0), so any
// contended atomic would serialize ALL waves at the barrier (R1 post-mortem:
// ~3000 cyc/step of atomic drain). Per-wave partials -> plain private stores.
__global__ __launch_bounds__(256, 1) void lstm_scan(
    const float* __restrict__ x,  const float* __restrict__ c0,
    const float* __restrict__ Wi, const float* __restrict__ bi,
    const float* __restrict__ Wf1,const float* __restrict__ bf1,
    const float* __restrict__ Wf2,const float* __restrict__ bf2,
    const float* __restrict__ Wg1,const float* __restrict__ bg1,
    const float* __restrict__ Wg2,const float* __restrict__ bg2,
    const float* __restrict__ Wo1,const float* __restrict__ bo1,
    const float* __restrict__ Wo2,const float* __restrict__ bo2,
    const float* __restrict__ Wl, float* __restrict__ out,
    unsigned* __restrict__ ring, float* __restrict__ part)
{
  const int tid = threadIdx.x;
  const int jl  = tid >> 4;
  const int s   = tid & 15;
  const int jg  = blockIdx.x * JPW + jl;

  // h staging: chunk s lives at dword s*36 (32 data + 4 pad) -> ds_read_b128
  // bank pattern is 2-way (free, m136) instead of 16-way without padding.
  __shared__ __align__(16) float hbuf[2][16 * 36];
  __shared__ float4 xbuf[2][12];   // one 48-float x row, double-buffered

  // ---- load recurrent weight slices into registers (one-time) ----
  float4 wf[8], wg[8], wo[8];
  {
    const float4* pf = (const float4*)(Wf2 + jg * HID + s * 32);
    const float4* pg = (const float4*)(Wg2 + jg * HID + s * 32);
    const float4* po = (const float4*)(Wo2 + jg * HID + s * 32);
#pragma unroll
    for (int r = 0; r < 8; ++r) { wf[r] = pf[r]; wg[r] = pg[r]; wo[r] = po[r]; }
  }
  // ---- x-projection weights: s==0 -> i-gate (32 wide), s==1/2/3 -> f/g/o (16 wide)
  float4 wx[8];
  float xb = 0.f;
#pragma unroll
  for (int r = 0; r < 8; ++r) wx[r] = make_float4(0.f, 0.f, 0.f, 0.f);
  if (s == 0) {
    const float4* p = (const float4*)(Wi + jg * 32);
#pragma unroll
    for (int r = 0; r < 8; ++r) wx[r] = p[r];
    xb = bi[jg];
  } else if (s == 1) {
    const float4* p = (const float4*)(Wf1 + jg * 16);
#pragma unroll
    for (int r = 0; r < 4; ++r) wx[r] = p[r];
    xb = bf1[jg] + bf2[jg];
  } else if (s == 2) {
    const float4* p = (const float4*)(Wg1 + jg * 16);
#pragma unroll
    for (int r = 0; r < 4; ++r) wx[r] = p[r];
    xb = bg1[jg] + bg2[jg];
  } else if (s == 3) {
    const float4* p = (const float4*)(Wo1 + jg * 16);
#pragma unroll
    for (int r = 0; r < 4; ++r) wx[r] = p[r];
    xb = bo1[jg] + bo2[jg];
  }

  float cst = c0[jg];          // cell state (meaningful on s==0 lanes)
  const float wl = Wl[jg];

  // x prefetch, distance 2: xbuf[0] <- x[0]; xpre <- x[1]
  float4 xpre = make_float4(0.f, 0.f, 0.f, 0.f);
  if (tid < 12) {
    xbuf[0][tid] = *(const float4*)(x + 4 * tid);
    xpre = *(const float4*)(x + 48 + 4 * tid);
  }
  __syncthreads();

  for (int t = 0; t < T_STEPS; ++t) {
    // 1) stage x[t+1] (regs->LDS), kick off load of x[t+2]
    if (tid < 12) {
      xbuf[(t + 1) & 1][tid] = xpre;
      int tn = (t + 2 < T_STEPS) ? t + 2 : T_STEPS - 1;
      xpre = *(const float4*)(x + tn * 48 + 4 * tid);
    }
    // 2) x projections — computed in the shadow of h_{t-1} visibility latency
    float pr = xb;
    if (s < 4) {
      const float4* xv = &xbuf[t & 1][(s == 0) ? 4 : 0];
#pragma unroll
      for (int r = 0; r < 4; ++r) {
        float4 v = xv[r], w = wx[r];
        pr = fmaf(w.x, v.x, pr); pr = fmaf(w.y, v.y, pr);
        pr = fmaf(w.z, v.z, pr); pr = fmaf(w.w, v.w, pr);
      }
      if (s == 0) {
#pragma unroll
        for (int r = 4; r < 8; ++r) {
          float4 v = xv[r], w = wx[r];
          pr = fmaf(w.x, v.x, pr); pr = fmaf(w.y, v.y, pr);
          pr = fmaf(w.z, v.z, pr); pr = fmaf(w.w, v.w, pr);
        }
      }
    }
    float accf = (s == 1) ? pr : 0.f;
    float accg = (s == 2) ? pr : 0.f;
    float acco = (s == 3) ? pr : 0.f;
    const float ipre = pr;   // i-gate preact (valid on s==0)

    // 3) poll h_{t-1}: thread tid owns ring words [4tid,4tid+4) = elems 2tid,2tid+1
    const unsigned want = (unsigned)(t + 1);          // tag of h_{t-1}
    const unsigned* pw =
        ring + (((unsigned)(t - 1)) & (RING_D - 1)) * RING_W + 4 * tid;
    unsigned a, b, c2, d2;
    do {
      a  = ld_ring(pw);     b  = ld_ring(pw + 1);
      c2 = ld_ring(pw + 2); d2 = ld_ring(pw + 3);
    } while (((a ^ want) | (b ^ want) | (c2 ^ want) | (d2 ^ want)) & 0xFFFFu);
    unsigned bits0 = (a  & 0xFFFF0000u) | (b  >> 16);
    unsigned bits1 = (c2 & 0xFFFF0000u) | (d2 >> 16);
    {
      int idx = 2 * tid + 4 * (tid >> 4);             // swizzled: elem e -> e + 4*(e>>5)
      *(float2*)(&hbuf[t & 1][idx]) =
          make_float2(__uint_as_float(bits0), __uint_as_float(bits1));
    }
    __syncthreads();   // the ONLY barrier per step

    // 4) gate dots: 3 gates x 32 k-elems from VGPR weights, h from LDS
    const float* hb = &hbuf[t & 1][s * 36];
#pragma unroll
    for (int r = 0; r < 8; ++r) {
      float4 hv = *(const float4*)(hb + 4 * r);
      accf = fmaf(wf[r].x, hv.x, accf); accf = fmaf(wf[r].y, hv.y, accf);
      accf = fmaf(wf[r].z, hv.z, accf); accf = fmaf(wf[r].w, hv.w, accf);
      accg = fmaf(wg[r].x, hv.x, accg); accg = fmaf(wg[r].y, hv.y, accg);
      accg = fmaf(wg[r].z, hv.z, accg); accg = fmaf(wg[r].w, hv.w, accg);
      acco = fmaf(wo[r].x, hv.x, acco); acco = fmaf(wo[r].y, hv.y, acco);
      acco = fmaf(wo[r].z, hv.z, acco); acco = fmaf(wo[r].w, hv.w, acco);
    }
    // 5) butterfly reduce over the 16 k-split lanes (all lanes get the sum)
#pragma unroll
    for (int m = 1; m <= 8; m <<= 1) {
      accf += __shfl_xor(accf, m, 16);
      accg += __shfl_xor(accg, m, 16);
      acco += __shfl_xor(acco, m, 16);
    }
    // 6) gates + state update (computed on all lanes; only s==0 is meaningful)
    float f  = sigf(accf);
    float g  = tanhfast(accg);
    float o  = sigf(acco);
    float it = sigf(ipre);
    cst = fmaf(f, cst, it * g);
    float hj = o * tanhfast(cst);

    // 7) publish h_t as two tagged words (relaxed agent-scope; self-validating)
    if (s == 0) {
      unsigned bits = __float_as_uint(hj);
      unsigned tag  = (unsigned)(t + 2);
      unsigned* dst = ring + (t & (RING_D - 1)) * RING_W + 2 * jg;
      st_ring(dst,     (bits & 0xFFFF0000u) | tag);
      st_ring(dst + 1, (bits << 16) | tag);
    }
    // 8) out[t] partial: wave-reduce the 4 owner lanes, then ONE private
    //    plain store per wave (no contention, no RMW; drained cheaply at the
    //    next barrier). Fallback to atomics only if ws too small.
    float val = (s == 0) ? wl * hj : 0.f;
    val += __shfl_xor(val, 16, 64);
    val += __shfl_xor(val, 32, 64);
    if ((tid & 63) == 0) {
      if (part) {
        part[(blockIdx.x * 4 + (tid >> 6)) * T_STEPS + t] = val;
      } else {
        atomicAdd(out + t, val);
      }
    }
  }
}

extern "C" void kernel_launch(void* const* d_in, const int* in_sizes, int n_in,
                              void* d_out, int out_size, void* d_ws, size_t ws_size,
                              hipStream_t stream) {
  const float* x   = (const float*)d_in[0];
  const float* h0  = (const float*)d_in[1];
  const float* c0  = (const float*)d_in[2];
  const float* Wi  = (const float*)d_in[3];
  const float* bi  = (const float*)d_in[4];
  const float* Wf1 = (const float*)d_in[5];
  const float* bf1 = (const float*)d_in[6];
  const float* Wf2 = (const float*)d_in[7];
  const float* bf2 = (const float*)d_in[8];
  const float* Wg1 = (const float*)d_in[9];
  const float* bg1 = (const float*)d_in[10];
  const float* Wg2 = (const float*)d_in[11];
  const float* bg2 = (const float*)d_in[12];
  const float* Wo1 = (const float*)d_in[13];
  const float* bo1 = (const float*)d_in[14];
  const float* Wo2 = (const float*)d_in[15];
  const float* bo2 = (const float*)d_in[16];
  const float* Wl  = (const float*)d_in[17];
  const float* bl  = (const float*)d_in[18];
  float* out = (float*)d_out;

  unsigned* ring = (unsigned*)d_ws;                 // 32 KiB
  size_t ring_bytes = (size_t)RING_D * RING_W * 4;
  size_t part_bytes = (size_t)NPART * T_STEPS * 4;  // 8 MiB
  float* part = (ws_size >= ring_bytes + part_bytes)
                    ? (float*)((char*)d_ws + ring_bytes)
                    : nullptr;

  hipLaunchKernelGGL(init_kernel, dim3(64), dim3(256), 0, stream, out, ring, h0, bl);
  hipLaunchKernelGGL(lstm_scan, dim3(NWG), dim3(256), 0, stream,
                     x, c0, Wi, bi, Wf1, bf1, Wf2, bf2, Wg1, bg1, Wg2, bg2,
                     Wo1, bo1, Wo2, bo2, Wl, out, ring, part);
  if (part) {
    hipLaunchKernelGGL(finalize_kernel, dim3(T_STEPS / 256), dim3(256), 0, stream,
                       part, bl, out);
  }
}